// Round 7
// baseline (8942.545 us; speedup 1.0000x reference)
//
#include <hip/hip_runtime.h>
#include <stdint.h>

#define TMAX 8192
#define H 128

typedef _Float16 half2_t __attribute__((ext_vector_type(2)));

__device__ __forceinline__ float sigf(float x)       { return 1.f / (1.f + __expf(-x)); }
__device__ __forceinline__ float tanhf_fast(float x) { return 2.f / (1.f + __expf(-2.f * x)) - 1.f; }

// v += value from lane (this ^ pattern) — VALU DPP, no DS pipe.
template<int CTRL>
__device__ __forceinline__ float dppadd(float v) {
    return v + __int_as_float(__builtin_amdgcn_update_dpp(
        0, __float_as_int(v), CTRL, 0xf, 0xf, true));
}

#if __has_builtin(__builtin_amdgcn_fdot2)
__device__ __forceinline__ float fdot2(half2_t a, half2_t b, float c) {
    return __builtin_amdgcn_fdot2(a, b, c, false);
}
#else
__device__ __forceinline__ float fdot2(half2_t a, half2_t b, float c) {
    return fmaf((float)a.x, (float)b.x, fmaf((float)a.y, (float)b.y, c));
}
#endif

// 1024 threads, 16 waves. Octet lane g = l&7 owns k in [16g,16g+16);
// octet j = w*8 + (l>>3) in 0..127 owns rows {j,j+128,j+256,j+384} = the
// i|f|g|o quad of output j. Weights f16-packed: 4 rows x 8 half2 = 32 VGPRs
// -> total ~60 VGPRs, UNDER the RA's 64-reg pressure target (8 waves/EU),
// so no spill/AGPR-shuffle by construction (r2-r6 failure mode).
// v_dot2_f32_f16: 2 MACs/instr, fp32 accumulate. DPP octet butterfly
// completes the gate quad in-lane: no gate LDS, one barrier/step.
__global__ __launch_bounds__(1024)
void lstm_seq_kernel(const float* __restrict__ x,
                     const float* __restrict__ Wih,
                     const float* __restrict__ Whh,
                     const float* __restrict__ bih,
                     const float* __restrict__ bhh,
                     const float* __restrict__ Wlin,
                     const float* __restrict__ blin,
                     const float* __restrict__ h0,
                     const float* __restrict__ c0,
                     float* __restrict__ out,
                     int T)
{
    __shared__ float x_s[TMAX];                     // 32 KB
    __shared__ __align__(16) _Float16 hbuf[2][H];   // double-buffered h, f16 (512 B)

    const int t = threadIdx.x;          // 0..1023
    const int w = t >> 6;               // wave 0..15
    const int l = t & 63;
    const int g = l & 7;                // k-group: k in [16g, 16g+16)
    const int j = w * 8 + (l >> 3);     // output index 0..127

    // Stage input sequence into LDS (one-time, coalesced).
    for (int i = t; i < T; i += 1024) x_s[i] = x[i];

    // Weights: rows j+128r (r=0..3 -> i,f,g,o), k-slice [16g,16g+16), f16x2.
    uint32_t wv[32];
    #pragma unroll
    for (int r = 0; r < 4; ++r) {
        const float* src = Whh + (j + 128 * r) * H + 16 * g;
        #pragma unroll
        for (int p = 0; p < 8; ++p) {
            half2_t h2;
            h2.x = (_Float16)src[2 * p];
            h2.y = (_Float16)src[2 * p + 1];
            wv[r * 8 + p] = __builtin_bit_cast(uint32_t, h2);
        }
    }
    #pragma unroll
    for (int i = 0; i < 32; ++i) asm volatile("" : "+v"(wv[i]));

    // Per-output x-weights and fused biases (uniform within the octet).
    float wih[4], bs[4];
    #pragma unroll
    for (int r = 0; r < 4; ++r) {
        wih[r] = Wih[j + 128 * r];
        bs[r]  = bih[j + 128 * r] + bhh[j + 128 * r];
    }
    float c = c0[j];

    if (t < H) hbuf[0][t] = (_Float16)h0[t];
    __syncthreads();

    const int hoff = 16 * g;            // this lane's k-slice of h (halves)

    for (int step = 0; step < T; ++step) {
        const int b = step & 1;
        // 16 halves = 2 x ds_read_b128; 32B stride across g -> 2-way bank
        // aliasing only (free).
        const uint4* hp = (const uint4*)&hbuf[b][hoff];
        const uint4 ha = hp[0], hb = hp[1];
        const uint32_t hh[8] = {ha.x, ha.y, ha.z, ha.w, hb.x, hb.y, hb.z, hb.w};

        float acc[4];
        #pragma unroll
        for (int r = 0; r < 4; ++r) {
            float s = 0.f;
            #pragma unroll
            for (int p = 0; p < 8; ++p)
                s = fdot2(__builtin_bit_cast(half2_t, wv[r * 8 + p]),
                          __builtin_bit_cast(half2_t, hh[p]), s);
            acc[r] = s;
        }

        // Octet butterfly: lane^1 (quad_perm), lane^2 (quad_perm),
        // lane^7-within-8 (row_half_mirror). All 8 lanes end complete.
        #pragma unroll
        for (int r = 0; r < 4; ++r) {
            acc[r] = dppadd<0xB1>(acc[r]);
            acc[r] = dppadd<0x4E>(acc[r]);
            acc[r] = dppadd<0x141>(acc[r]);
        }

        const float xv = x_s[step];
        const float gi = acc[0] + fmaf(xv, wih[0], bs[0]);
        const float gf = acc[1] + fmaf(xv, wih[1], bs[1]);
        const float gg = acc[2] + fmaf(xv, wih[2], bs[2]);
        const float go = acc[3] + fmaf(xv, wih[3], bs[3]);
        const float ig = sigf(gi);
        const float fg = sigf(gf);
        const float gt = tanhf_fast(gg);
        const float og = sigf(go);
        c = fmaf(fg, c, ig * gt);
        const float hv = og * tanhf_fast(c);
        if (g == 0) hbuf[b ^ 1][j] = (_Float16)hv;
        __syncthreads();   // single barrier: h-writes vs next step's reads
    }

    // Final linear: out = dot(W_lin, h_T) + b_lin  (wave 0 only).
    if (t < 64) {
        const _Float16* hs = hbuf[T & 1];
        float v = Wlin[t] * (float)hs[t] + Wlin[t + 64] * (float)hs[t + 64];
        #pragma unroll
        for (int off = 32; off >= 1; off >>= 1) v += __shfl_down(v, off);
        if (t == 0) out[0] = v + blin[0];
    }
}

extern "C" void kernel_launch(void* const* d_in, const int* in_sizes, int n_in,
                              void* d_out, int out_size, void* d_ws, size_t ws_size,
                              hipStream_t stream) {
    const float* x    = (const float*)d_in[0];
    const float* Wih  = (const float*)d_in[1];
    const float* Whh  = (const float*)d_in[2];
    const float* bih  = (const float*)d_in[3];
    const float* bhh  = (const float*)d_in[4];
    const float* Wlin = (const float*)d_in[5];
    const float* blin = (const float*)d_in[6];
    const float* h0   = (const float*)d_in[7];
    const float* c0   = (const float*)d_in[8];
    float* out = (float*)d_out;
    const int T = in_sizes[0];

    lstm_seq_kernel<<<1, 1024, 0, stream>>>(x, Wih, Whh, bih, bhh, Wlin, blin,
                                            h0, c0, out, T);
}